// Round 4
// baseline (183.311 us; speedup 1.0000x reference)
//
#include <hip/hip_runtime.h>

typedef unsigned short u16;
typedef short short8 __attribute__((ext_vector_type(8)));
typedef float floatx4 __attribute__((ext_vector_type(4)));
typedef __bf16 bf16x2 __attribute__((ext_vector_type(2)));

#define MFMA16(a, b, c) __builtin_amdgcn_mfma_f32_16x16x32_bf16((a), (b), (c), 0, 0, 0)

// ---- g_ws byte offsets (256-aligned) ----
#define W1F_OFF   0u         // bf16[4096]
#define B1F_OFF   8192u      // f32[64]
#define W2F_OFF   8448u      // bf16[8192]
#define B2F_OFF   24832u     // f32[128]
#define WA0F_OFF  25344u     // bf16[8192]
#define BAF_OFF   41728u     // f32[64]
#define WA1F_OFF  41984u     // f32[64]
#define BA1F_OFF  42240u     // f32[1]
#define P_OFF     42496u     // f32[32*128*64]
#define Q_OFF     1091072u   // f32[32*128*64]
#define SC_OFF    2139648u   // f32[32*128*128]
#define WS_TOTAL  4236800u

__device__ __align__(256) char g_ws[WS_TOTAL];

__device__ __forceinline__ float bits2f(unsigned u) {
  union { unsigned i; float f; } v; v.i = u; return v.f;
}
__device__ __forceinline__ unsigned f2bits(float f) {
  union { float f; unsigned i; } v; v.f = f; return v.i;
}
__device__ __forceinline__ u16 f2bf(float f) {
  return (u16)((f2bits(f) + 0x8000u) >> 16);
}
// two fp32 -> relu -> packed bf16 pair. gfx950: 2 fmax + 1 v_cvt_pk_bf16_f32.
__device__ __forceinline__ unsigned pack2relu(float a, float b) {
#if __has_builtin(__builtin_amdgcn_cvt_pk_bf16_f32)
  union { bf16x2 h; unsigned u; } cv;
  cv.h = __builtin_amdgcn_cvt_pk_bf16_f32(fmaxf(a, 0.f), fmaxf(b, 0.f));
  return cv.u;
#else
  unsigned lo = (f2bits(fmaxf(a, 0.f)) + 0x8000u) >> 16;
  unsigned hi = (f2bits(fmaxf(b, 0.f)) + 0x8000u) & 0xffff0000u;
  return lo | hi;
#endif
}

// XOR-swizzled LDS addressing (u16 units). Row-major with natural stride,
// 16B chunk index XORed with (row&7) -> per-pattern bank arithmetic puts
// every b128/uint4/uint2 access at its theoretical bank-spread minimum.
__device__ __forceinline__ int sw64(int row, int col) {   // 64-col rows
  return (row << 6) + ((((col >> 3) ^ (row & 7)) << 3) | (col & 7));
}
__device__ __forceinline__ int sw128(int row, int col) {  // 128-col rows
  return (row << 7) + ((((col >> 3) ^ (row & 7)) << 3) | (col & 7));
}

// ------------------------------------------------------------------
// k_pre: 513 blocks x 256.  (unchanged)
//   blocks   0..255: P/Q for (b = sub>>3, n0 = (sub&7)*16)
//   blocks 256..511: SC  for same (b, n0)
//   block  512:      fold W1/W2/Wa0 (bf16) + biases
// ------------------------------------------------------------------
__global__ __launch_bounds__(256) void k_pre(
    const float* __restrict__ feat, const float* __restrict__ w0,
    const float* __restrict__ g0, const float* __restrict__ b0, const float* __restrict__ m0, const float* __restrict__ v0,
    const float* __restrict__ w1, const float* __restrict__ g1, const float* __restrict__ b1, const float* __restrict__ m1, const float* __restrict__ v1,
    const float* __restrict__ w2, const float* __restrict__ g2, const float* __restrict__ b2, const float* __restrict__ m2, const float* __restrict__ v2,
    const float* __restrict__ wa0, const float* __restrict__ ga, const float* __restrict__ ba, const float* __restrict__ ma, const float* __restrict__ va,
    const float* __restrict__ wa1, const float* __restrict__ ba1,
    const float* __restrict__ wsc, const float* __restrict__ gsc, const float* __restrict__ bsc, const float* __restrict__ msc, const float* __restrict__ vsc)
{
  __shared__ float smem[9600];
  const int t = threadIdx.x;
  char* ws = g_ws;
  const int blk = blockIdx.x;

  if (blk == 512) {
    float* fs1 = smem; float* fs2 = smem + 64; float* fsa = smem + 192;
    if (t < 64) {
      float s;
      s = g1[t] * rsqrtf(v1[t] + 1e-5f); fs1[t] = s; ((float*)(ws + B1F_OFF))[t] = b1[t] - m1[t] * s;
      s = ga[t] * rsqrtf(va[t] + 1e-5f); fsa[t] = s; ((float*)(ws + BAF_OFF))[t] = ba[t] - ma[t] * s;
      ((float*)(ws + WA1F_OFF))[t] = wa1[t];
    }
    if (t < 128) { float s = g2[t] * rsqrtf(v2[t] + 1e-5f); fs2[t] = s; ((float*)(ws + B2F_OFF))[t] = b2[t] - m2[t] * s; }
    if (t == 0) ((float*)(ws + BA1F_OFF))[0] = ba1[0];
    __syncthreads();
    u16* W1f = (u16*)(ws + W1F_OFF);
    u16* W2f = (u16*)(ws + W2F_OFF);
    u16* Wa0f = (u16*)(ws + WA0F_OFF);
    for (int i = t; i < 4096; i += 256) W1f[i]  = f2bf(fs1[i >> 6] * w1[i]);
    for (int i = t; i < 8192; i += 256) W2f[i]  = f2bf(fs2[i >> 6] * w2[i]);
    for (int i = t; i < 8192; i += 256) Wa0f[i] = f2bf(fsa[i >> 7] * wa0[i]);
    return;
  }

  const int sub = blk & 255;
  const int b = sub >> 3, n0 = (sub & 7) << 4;
  float* Xs  = smem;          // [64][20]
  float* Wsm = smem + 1280;

  {
    const int c = t >> 2, j = (t & 3) << 2;
    *(float4*)(Xs + c * 20 + j) = *(const float4*)(feat + b * 8192 + c * 128 + n0 + j);
  }

  if (blk < 256) {
    #pragma unroll
    for (int r = 0; r < 8; r++) {
      const int i = (r * 256 + t) * 4;
      float4 v = *(const float4*)(w0 + i);
      const int o = i >> 7, c = i & 127;
      float* d = Wsm + o * 129 + c;
      d[0] = v.x; d[1] = v.y; d[2] = v.z; d[3] = v.w;
    }
    __syncthreads();
    const int o = t & 63, nb = (t >> 6) << 2;
    const float s  = g0[o] * rsqrtf(v0[o] + 1e-5f);
    const float tt = b0[o] - m0[o] * s;
    const float* wr = Wsm + o * 129;
    float dA0=0.f,dA1=0.f,dA2=0.f,dA3=0.f,dB0=0.f,dB1=0.f,dB2=0.f,dB3=0.f;
    #pragma unroll
    for (int c = 0; c < 64; c++) {
      const float a = wr[c], e = wr[64 + c];
      const float4 x = *(const float4*)(Xs + c * 20 + nb);
      dA0 += a * x.x; dA1 += a * x.y; dA2 += a * x.z; dA3 += a * x.w;
      dB0 += e * x.x; dB1 += e * x.y; dB2 += e * x.z; dB3 += e * x.w;
    }
    float* Pp = (float*)(ws + P_OFF) + (b * 128 + n0 + nb) * 64 + o;
    float* Qp = (float*)(ws + Q_OFF) + (b * 128 + n0 + nb) * 64 + o;
    Pp[0]   = s * dB0; Pp[64]  = s * dB1; Pp[128] = s * dB2; Pp[192] = s * dB3;
    Qp[0]   = s * (dA0 - dB0) + tt; Qp[64]  = s * (dA1 - dB1) + tt;
    Qp[128] = s * (dA2 - dB2) + tt; Qp[192] = s * (dA3 - dB3) + tt;
  } else {
    #pragma unroll
    for (int r = 0; r < 8; r++) {
      const int i = (r * 256 + t) * 4;
      float4 v = *(const float4*)(wsc + i);
      const int o = i >> 6, c = i & 63;
      float* d = Wsm + o * 65 + c;
      d[0] = v.x; d[1] = v.y; d[2] = v.z; d[3] = v.w;
    }
    __syncthreads();
    const int o = t & 127, h = (t >> 7) << 3;
    const float s  = gsc[o] * rsqrtf(vsc[o] + 1e-5f);
    const float tt = bsc[o] - msc[o] * s;
    const float* wr = Wsm + o * 65;
    float d0=0.f,d1=0.f,d2=0.f,d3=0.f,d4=0.f,d5=0.f,d6=0.f,d7=0.f;
    #pragma unroll
    for (int c = 0; c < 64; c++) {
      const float a = wr[c];
      const float4 x0 = *(const float4*)(Xs + c * 20 + h);
      const float4 x1 = *(const float4*)(Xs + c * 20 + h + 4);
      d0 += a * x0.x; d1 += a * x0.y; d2 += a * x0.z; d3 += a * x0.w;
      d4 += a * x1.x; d5 += a * x1.y; d6 += a * x1.z; d7 += a * x1.w;
    }
    float* SCp = (float*)(ws + SC_OFF) + (b * 128 + n0 + h) * 128 + o;
    SCp[0]   = s * d0 + tt; SCp[128] = s * d1 + tt; SCp[256] = s * d2 + tt; SCp[384] = s * d3 + tt;
    SCp[512] = s * d4 + tt; SCp[640] = s * d5 + tt; SCp[768] = s * d6 + tt; SCp[896] = s * d7 + tt;
  }
}

// ------------------------------------------------------------------
// k_main R13 = R12 structure at 512 threads (8 waves): halve per-thread
// work, raise waves/SIMD 4 -> 6 (__launch_bounds__(512,6): 85-reg class;
// 8/SIMD needs <=64 total regs incl AGPR — infeasible with G2's acc).
// Wave w owns m-tile (w&3) and edge-half (w>>2) in every GEMM phase.
// Swizzles, barrier structure (7), A-frag hoisting, fts prefetch kept.
// ------------------------------------------------------------------
__global__ __launch_bounds__(512, 6) void k_main(float* __restrict__ out)
{
  __shared__ alignas(16) u16 buf[16384];     // H0@0, H1@8192; H2 overlays @0
  __shared__ float parts[8][128];            // G3 partials rows 0..3; fts rows 0..7
  __shared__ float attws[128];

  const int blk = blockIdx.x, b = blk >> 7, n = blk & 127, t = threadIdx.x;
  const char* ws = g_ws;
  const float* Pb  = (const float*)(ws + P_OFF);
  const float* Qb  = (const float*)(ws + Q_OFF);
  const float* SCb = (const float*)(ws + SC_OFF);
  const u16*   W1f = (const u16*)(ws + W1F_OFF);
  const float* b1f = (const float*)(ws + B1F_OFF);
  const u16*   W2f = (const u16*)(ws + W2F_OFF);
  const float* b2f = (const float*)(ws + B2F_OFF);
  const u16*   Wa0f= (const u16*)(ws + WA0F_OFF);
  const float* baf = (const float*)(ws + BAF_OFF);
  const float* wa1f= (const float*)(ws + WA1F_OFF);
  const float  ba1v= *(const float*)(ws + BA1F_OFF);

  u16* H0 = buf;
  u16* H1 = buf + 8192;
  u16* H2 = buf;            // after barrier (3)

  const int lane = t & 63, wid = t >> 6, quad = lane >> 4, l16 = lane & 15;
  const int koff = quad * 8;
  const int mt = wid & 3, eh = wid >> 2;   // m-tile, edge-half per wave
  const int c2 = mt * 32;                   // G2 channel base

  // hoisted A-fragments (global, L1-hot; no LDS dependence)
  const short8 a1w0 = *(const short8*)(W1f + (mt * 16 + l16) * 64 + koff);
  const short8 a1w1 = *(const short8*)(W1f + (mt * 16 + l16) * 64 + 32 + koff);
  const short8 a2w00 = *(const short8*)(W2f + (c2 + l16) * 64 + koff);
  const short8 a2w01 = *(const short8*)(W2f + (c2 + l16) * 64 + 32 + koff);
  const short8 a2w10 = *(const short8*)(W2f + (c2 + 16 + l16) * 64 + koff);
  const short8 a2w11 = *(const short8*)(W2f + (c2 + 16 + l16) * 64 + 32 + koff);

  // ---- L0: H0[edge][ch] = relu(Q[b,n] + P[b,j]); edge 127 dummy ----
  {
    const int k = t >> 2, q4 = t & 3;       // edge, 16-ch quarter
    const int j = (k < 127) ? ((k < n) ? k : (k + 1)) : n;
    const float4* pr = (const float4*)(Pb + ((b << 7) + j) * 64 + q4 * 16);
    const float4* qr = (const float4*)(Qb + blk * 64 + q4 * 16);
    float4 p0 = pr[0], p1 = pr[1], p2 = pr[2], p3 = pr[3];
    float4 q0 = qr[0], q1 = qr[1], q2 = qr[2], q3 = qr[3];
    uint4 s0, s1;
    s0.x = pack2relu(q0.x + p0.x, q0.y + p0.y);
    s0.y = pack2relu(q0.z + p0.z, q0.w + p0.w);
    s0.z = pack2relu(q1.x + p1.x, q1.y + p1.y);
    s0.w = pack2relu(q1.z + p1.z, q1.w + p1.w);
    s1.x = pack2relu(q2.x + p2.x, q2.y + p2.y);
    s1.y = pack2relu(q2.z + p2.z, q2.w + p2.w);
    s1.z = pack2relu(q3.x + p3.x, q3.y + p3.y);
    s1.w = pack2relu(q3.z + p3.z, q3.w + p3.w);
    *(uint4*)(H0 + sw64(k, q4 * 16))     = s0;
    *(uint4*)(H0 + sw64(k, q4 * 16 + 8)) = s1;
  }
  __syncthreads();                                           // (1)

  // ---- GEMM1: wave (mt, eh): out-ch mt*16..+15, edges eh*64..+63 ----
  {
    const float4 bb = *(const float4*)(b1f + mt * 16 + quad * 4);
    floatx4 binit; binit[0] = bb.x; binit[1] = bb.y; binit[2] = bb.z; binit[3] = bb.w;
    floatx4 acc[4];
    #pragma unroll
    for (int i = 0; i < 4; i++) acc[i] = binit;
    #pragma unroll
    for (int i = 0; i < 4; i++) {
      const int row = eh * 64 + i * 16 + l16;
      short8 bf0 = *(const short8*)(H0 + sw64(row, koff));
      short8 bf1 = *(const short8*)(H0 + sw64(row, koff + 32));
      acc[i] = MFMA16(a1w0, bf0, acc[i]);
      acc[i] = MFMA16(a1w1, bf1, acc[i]);
    }
    #pragma unroll
    for (int i = 0; i < 4; i++) {
      uint2 sv;
      sv.x = pack2relu(acc[i][0], acc[i][1]);
      sv.y = pack2relu(acc[i][2], acc[i][3]);
      *(uint2*)(H1 + sw64(eh * 64 + i * 16 + l16, mt * 16 + quad * 4)) = sv;
    }
  }
  __syncthreads();                                           // (2)

  // ---- GEMM2: wave (mt, eh): out-ch c2..+31, edges eh*64..+63 ----
  {
    const float4 bba = *(const float4*)(b2f + c2 + quad * 4);
    const float4 bbb = *(const float4*)(b2f + c2 + 16 + quad * 4);
    floatx4 ia; ia[0] = bba.x; ia[1] = bba.y; ia[2] = bba.z; ia[3] = bba.w;
    floatx4 ib; ib[0] = bbb.x; ib[1] = bbb.y; ib[2] = bbb.z; ib[3] = bbb.w;
    floatx4 acc[2][4];
    #pragma unroll
    for (int i = 0; i < 4; i++) { acc[0][i] = ia; acc[1][i] = ib; }
    #pragma unroll
    for (int i = 0; i < 4; i++) {
      const int row = eh * 64 + i * 16 + l16;
      short8 bf0 = *(const short8*)(H1 + sw64(row, koff));
      short8 bf1 = *(const short8*)(H1 + sw64(row, koff + 32));
      acc[0][i] = MFMA16(a2w00, bf0, acc[0][i]);
      acc[0][i] = MFMA16(a2w01, bf1, acc[0][i]);
      acc[1][i] = MFMA16(a2w10, bf0, acc[1][i]);
      acc[1][i] = MFMA16(a2w11, bf1, acc[1][i]);
    }
    __syncthreads();                                         // (3) H0/H1 reads done
    #pragma unroll
    for (int m = 0; m < 2; m++) {
      const int cc = c2 + m * 16 + quad * 4;
      #pragma unroll
      for (int i = 0; i < 4; i++) {
        uint2 sv;
        sv.x = pack2relu(acc[m][i][0], acc[m][i][1]);
        sv.y = pack2relu(acc[m][i][2], acc[m][i][3]);
        *(uint2*)(H2 + sw128(eh * 64 + i * 16 + l16, cc)) = sv;
      }
    }
  }

  // hoisted G3 A-frags (global, L1-hot — issue before the barrier)
  short8 a3[4];
  #pragma unroll
  for (int ks = 0; ks < 4; ks++)
    a3[ks] = *(const short8*)(Wa0f + (mt * 16 + l16) * 128 + ks * 32 + koff);

  __syncthreads();                                           // (4)

  // hoisted epilogue loads (overlap with GEMM3/softmax/fts)
  float scv = 0.f;
  if (t < 128) scv = SCb[blk * 128 + t];
  float* outp = out + ((b << 7) + (t & 127)) * 128 + n;

  // ---- GEMM3 + logits: wave (mt, eh): att-ch mt*16..+15 partial ----
  {
    const float4 bb = *(const float4*)(baf + mt * 16 + quad * 4);
    const float4 wv = *(const float4*)(wa1f + mt * 16 + quad * 4);
    floatx4 binit; binit[0] = bb.x; binit[1] = bb.y; binit[2] = bb.z; binit[3] = bb.w;
    floatx4 acc[4];
    #pragma unroll
    for (int i = 0; i < 4; i++) acc[i] = binit;
    #pragma unroll
    for (int i = 0; i < 4; i++) {
      const int row = eh * 64 + i * 16 + l16;
      #pragma unroll
      for (int ks = 0; ks < 4; ks++) {
        short8 bf = *(const short8*)(H2 + sw128(row, koff + ks * 32));
        acc[i] = MFMA16(a3[ks], bf, acc[i]);
      }
    }
    #pragma unroll
    for (int i = 0; i < 4; i++) {
      float p = wv.x * fmaxf(acc[i][0], 0.f) + wv.y * fmaxf(acc[i][1], 0.f)
              + wv.z * fmaxf(acc[i][2], 0.f) + wv.w * fmaxf(acc[i][3], 0.f);
      p += __shfl_xor(p, 16); p += __shfl_xor(p, 32);
      if (quad == 0) parts[mt][eh * 64 + i * 16 + l16] = p;
    }
  }

  // ---- fts prefetch: H2 final since barrier (4); pull this thread's
  //      4 rows now so the LDS latency overlaps the softmax barriers ----
  const int chg = t & 15, eg = t >> 4;   // 8 ch x 4 edges per thread
  uint4 hv[4];
  #pragma unroll
  for (int i = 0; i < 4; i++)
    hv[i] = *(const uint4*)(H2 + sw128(eg * 4 + i, chg * 8));

  __syncthreads();                                           // (5)

  // ---- softmax over 127 edges (wave 0) ----
  if (wid == 0) {
    float a0 = parts[0][lane] + parts[1][lane] + parts[2][lane] + parts[3][lane] + ba1v;
    float a1 = (lane == 63) ? -1e30f
             : (parts[0][lane + 64] + parts[1][lane + 64] + parts[2][lane + 64] + parts[3][lane + 64] + ba1v);
    float mx = fmaxf(a0, a1);
    #pragma unroll
    for (int off = 32; off >= 1; off >>= 1) mx = fmaxf(mx, __shfl_xor(mx, off));
    float e0 = expf(a0 - mx), e1 = expf(a1 - mx);
    float sm = e0 + e1;
    #pragma unroll
    for (int off = 32; off >= 1; off >>= 1) sm += __shfl_xor(sm, off);
    float inv = 1.f / sm;
    attws[lane] = e0 * inv;
    attws[lane + 64] = e1 * inv;   // attw[127] = 0
  }
  __syncthreads();                                           // (6)

  // ---- fts[c] = sum_e attw[e]*H2[e][c]  (H2 values already in hv) ----
  {
    float fa[8];
    #pragma unroll
    for (int k = 0; k < 8; k++) fa[k] = 0.f;
    #pragma unroll
    for (int i = 0; i < 4; i++) {
      const float w = attws[eg * 4 + i];
      uint4 v = hv[i];
      unsigned u;
      u = v.x; fa[0] += w * bits2f(u << 16); fa[1] += w * bits2f(u & 0xffff0000u);
      u = v.y; fa[2] += w * bits2f(u << 16); fa[3] += w * bits2f(u & 0xffff0000u);
      u = v.z; fa[4] += w * bits2f(u << 16); fa[5] += w * bits2f(u & 0xffff0000u);
      u = v.w; fa[6] += w * bits2f(u << 16); fa[7] += w * bits2f(u & 0xffff0000u);
    }
    #pragma unroll
    for (int k = 0; k < 8; k++) { fa[k] += __shfl_xor(fa[k], 16); fa[k] += __shfl_xor(fa[k], 32); }
    if (lane < 16) {
      #pragma unroll
      for (int k = 0; k < 8; k++) parts[wid][chg * 8 + k] = fa[k];
    }
  }
  __syncthreads();                                           // (7)

  if (t < 128) {
    float fts = parts[0][t] + parts[1][t] + parts[2][t] + parts[3][t]
              + parts[4][t] + parts[5][t] + parts[6][t] + parts[7][t];
    *outp = fmaxf(scv + fts, 0.f);
  }
}

// ------------------------------------------------------------------
extern "C" void kernel_launch(void* const* d_in, const int* in_sizes, int n_in,
                              void* d_out, int out_size, void* d_ws, size_t ws_size,
                              hipStream_t stream)
{
  (void)d_ws; (void)ws_size; (void)in_sizes; (void)n_in; (void)out_size;
  const float* feat = (const float*)d_in[0];
  const float *w0 = (const float*)d_in[1],  *g0 = (const float*)d_in[2],  *b0 = (const float*)d_in[3],  *m0 = (const float*)d_in[4],  *v0 = (const float*)d_in[5];
  const float *w1 = (const float*)d_in[6],  *g1 = (const float*)d_in[7],  *b1 = (const float*)d_in[8],  *m1 = (const float*)d_in[9],  *v1 = (const float*)d_in[10];
  const float *w2 = (const float*)d_in[11], *g2 = (const float*)d_in[12], *b2 = (const float*)d_in[13], *m2 = (const float*)d_in[14], *v2 = (const float*)d_in[15];
  const float *wa0= (const float*)d_in[16], *ga = (const float*)d_in[17], *ba = (const float*)d_in[18], *ma = (const float*)d_in[19], *va = (const float*)d_in[20];
  const float *wa1= (const float*)d_in[21], *ba1= (const float*)d_in[22];
  const float *wsc= (const float*)d_in[23], *gsc= (const float*)d_in[24], *bsc= (const float*)d_in[25], *msc= (const float*)d_in[26], *vsc= (const float*)d_in[27];

  k_pre<<<dim3(513), dim3(256), 0, stream>>>(
      feat, w0, g0, b0, m0, v0, w1, g1, b1, m1, v1, w2, g2, b2, m2, v2,
      wa0, ga, ba, ma, va, wa1, ba1, wsc, gsc, bsc, msc, vsc);
  k_main<<<dim3(4096), dim3(512), 0, stream>>>((float*)d_out);
}

// Round 5
// 178.281 us; speedup vs baseline: 1.0282x; 1.0282x over previous
//
#include <hip/hip_runtime.h>

typedef unsigned short u16;
typedef short short8 __attribute__((ext_vector_type(8)));
typedef float floatx4 __attribute__((ext_vector_type(4)));
typedef __bf16 bf16x2 __attribute__((ext_vector_type(2)));

#define MFMA16(a, b, c) __builtin_amdgcn_mfma_f32_16x16x32_bf16((a), (b), (c), 0, 0, 0)

// ---- g_ws byte offsets (256-aligned) ----
#define W1F_OFF   0u         // bf16[4096]
#define B1F_OFF   8192u      // f32[64]
#define W2F_OFF   8448u      // bf16[8192]
#define B2F_OFF   24832u     // f32[128]
#define WA0F_OFF  25344u     // bf16[8192]
#define BAF_OFF   41728u     // f32[64]
#define WA1F_OFF  41984u     // f32[64]
#define BA1F_OFF  42240u     // f32[1]
#define P_OFF     42496u     // f32[32*128*64]
#define Q_OFF     1091072u   // f32[32*128*64]
#define SC_OFF    2139648u   // f32[32*128*128]
#define WS_TOTAL  4236800u

__device__ __align__(256) char g_ws[WS_TOTAL];

__device__ __forceinline__ float bits2f(unsigned u) {
  union { unsigned i; float f; } v; v.i = u; return v.f;
}
__device__ __forceinline__ unsigned f2bits(float f) {
  union { float f; unsigned i; } v; v.f = f; return v.i;
}
__device__ __forceinline__ u16 f2bf(float f) {
  return (u16)((f2bits(f) + 0x8000u) >> 16);
}
// two fp32 -> relu -> packed bf16 pair. gfx950: 2 fmax + 1 v_cvt_pk_bf16_f32.
__device__ __forceinline__ unsigned pack2relu(float a, float b) {
#if __has_builtin(__builtin_amdgcn_cvt_pk_bf16_f32)
  union { bf16x2 h; unsigned u; } cv;
  cv.h = __builtin_amdgcn_cvt_pk_bf16_f32(fmaxf(a, 0.f), fmaxf(b, 0.f));
  return cv.u;
#else
  unsigned lo = (f2bits(fmaxf(a, 0.f)) + 0x8000u) >> 16;
  unsigned hi = (f2bits(fmaxf(b, 0.f)) + 0x8000u) & 0xffff0000u;
  return lo | hi;
#endif
}

// XOR-swizzled LDS addressing (u16 units). Row-major with natural stride,
// 16B chunk index XORed with (row&7) -> per-pattern bank arithmetic puts
// every b128/uint4/uint2 access at its theoretical bank-spread minimum.
__device__ __forceinline__ int sw64(int row, int col) {   // 64-col rows
  return (row << 6) + ((((col >> 3) ^ (row & 7)) << 3) | (col & 7));
}
__device__ __forceinline__ int sw128(int row, int col) {  // 128-col rows
  return (row << 7) + ((((col >> 3) ^ (row & 7)) << 3) | (col & 7));
}

// ------------------------------------------------------------------
// k_pre: 513 blocks x 256.  (unchanged)
// ------------------------------------------------------------------
__global__ __launch_bounds__(256) void k_pre(
    const float* __restrict__ feat, const float* __restrict__ w0,
    const float* __restrict__ g0, const float* __restrict__ b0, const float* __restrict__ m0, const float* __restrict__ v0,
    const float* __restrict__ w1, const float* __restrict__ g1, const float* __restrict__ b1, const float* __restrict__ m1, const float* __restrict__ v1,
    const float* __restrict__ w2, const float* __restrict__ g2, const float* __restrict__ b2, const float* __restrict__ m2, const float* __restrict__ v2,
    const float* __restrict__ wa0, const float* __restrict__ ga, const float* __restrict__ ba, const float* __restrict__ ma, const float* __restrict__ va,
    const float* __restrict__ wa1, const float* __restrict__ ba1,
    const float* __restrict__ wsc, const float* __restrict__ gsc, const float* __restrict__ bsc, const float* __restrict__ msc, const float* __restrict__ vsc)
{
  __shared__ float smem[9600];
  const int t = threadIdx.x;
  char* ws = g_ws;
  const int blk = blockIdx.x;

  if (blk == 512) {
    float* fs1 = smem; float* fs2 = smem + 64; float* fsa = smem + 192;
    if (t < 64) {
      float s;
      s = g1[t] * rsqrtf(v1[t] + 1e-5f); fs1[t] = s; ((float*)(ws + B1F_OFF))[t] = b1[t] - m1[t] * s;
      s = ga[t] * rsqrtf(va[t] + 1e-5f); fsa[t] = s; ((float*)(ws + BAF_OFF))[t] = ba[t] - ma[t] * s;
      ((float*)(ws + WA1F_OFF))[t] = wa1[t];
    }
    if (t < 128) { float s = g2[t] * rsqrtf(v2[t] + 1e-5f); fs2[t] = s; ((float*)(ws + B2F_OFF))[t] = b2[t] - m2[t] * s; }
    if (t == 0) ((float*)(ws + BA1F_OFF))[0] = ba1[0];
    __syncthreads();
    u16* W1f = (u16*)(ws + W1F_OFF);
    u16* W2f = (u16*)(ws + W2F_OFF);
    u16* Wa0f = (u16*)(ws + WA0F_OFF);
    for (int i = t; i < 4096; i += 256) W1f[i]  = f2bf(fs1[i >> 6] * w1[i]);
    for (int i = t; i < 8192; i += 256) W2f[i]  = f2bf(fs2[i >> 6] * w2[i]);
    for (int i = t; i < 8192; i += 256) Wa0f[i] = f2bf(fsa[i >> 7] * wa0[i]);
    return;
  }

  const int sub = blk & 255;
  const int b = sub >> 3, n0 = (sub & 7) << 4;
  float* Xs  = smem;          // [64][20]
  float* Wsm = smem + 1280;

  {
    const int c = t >> 2, j = (t & 3) << 2;
    *(float4*)(Xs + c * 20 + j) = *(const float4*)(feat + b * 8192 + c * 128 + n0 + j);
  }

  if (blk < 256) {
    #pragma unroll
    for (int r = 0; r < 8; r++) {
      const int i = (r * 256 + t) * 4;
      float4 v = *(const float4*)(w0 + i);
      const int o = i >> 7, c = i & 127;
      float* d = Wsm + o * 129 + c;
      d[0] = v.x; d[1] = v.y; d[2] = v.z; d[3] = v.w;
    }
    __syncthreads();
    const int o = t & 63, nb = (t >> 6) << 2;
    const float s  = g0[o] * rsqrtf(v0[o] + 1e-5f);
    const float tt = b0[o] - m0[o] * s;
    const float* wr = Wsm + o * 129;
    float dA0=0.f,dA1=0.f,dA2=0.f,dA3=0.f,dB0=0.f,dB1=0.f,dB2=0.f,dB3=0.f;
    #pragma unroll
    for (int c = 0; c < 64; c++) {
      const float a = wr[c], e = wr[64 + c];
      const float4 x = *(const float4*)(Xs + c * 20 + nb);
      dA0 += a * x.x; dA1 += a * x.y; dA2 += a * x.z; dA3 += a * x.w;
      dB0 += e * x.x; dB1 += e * x.y; dB2 += e * x.z; dB3 += e * x.w;
    }
    float* Pp = (float*)(ws + P_OFF) + (b * 128 + n0 + nb) * 64 + o;
    float* Qp = (float*)(ws + Q_OFF) + (b * 128 + n0 + nb) * 64 + o;
    Pp[0]   = s * dB0; Pp[64]  = s * dB1; Pp[128] = s * dB2; Pp[192] = s * dB3;
    Qp[0]   = s * (dA0 - dB0) + tt; Qp[64]  = s * (dA1 - dB1) + tt;
    Qp[128] = s * (dA2 - dB2) + tt; Qp[192] = s * (dA3 - dB3) + tt;
  } else {
    #pragma unroll
    for (int r = 0; r < 8; r++) {
      const int i = (r * 256 + t) * 4;
      float4 v = *(const float4*)(wsc + i);
      const int o = i >> 6, c = i & 63;
      float* d = Wsm + o * 65 + c;
      d[0] = v.x; d[1] = v.y; d[2] = v.z; d[3] = v.w;
    }
    __syncthreads();
    const int o = t & 127, h = (t >> 7) << 3;
    const float s  = gsc[o] * rsqrtf(vsc[o] + 1e-5f);
    const float tt = bsc[o] - msc[o] * s;
    const float* wr = Wsm + o * 65;
    float d0=0.f,d1=0.f,d2=0.f,d3=0.f,d4=0.f,d5=0.f,d6=0.f,d7=0.f;
    #pragma unroll
    for (int c = 0; c < 64; c++) {
      const float a = wr[c];
      const float4 x0 = *(const float4*)(Xs + c * 20 + h);
      const float4 x1 = *(const float4*)(Xs + c * 20 + h + 4);
      d0 += a * x0.x; d1 += a * x0.y; d2 += a * x0.z; d3 += a * x0.w;
      d4 += a * x1.x; d5 += a * x1.y; d6 += a * x1.z; d7 += a * x1.w;
    }
    float* SCp = (float*)(ws + SC_OFF) + (b * 128 + n0 + h) * 128 + o;
    SCp[0]   = s * d0 + tt; SCp[128] = s * d1 + tt; SCp[256] = s * d2 + tt; SCp[384] = s * d3 + tt;
    SCp[512] = s * d4 + tt; SCp[640] = s * d5 + tt; SCp[768] = s * d6 + tt; SCp[896] = s * d7 + tt;
  }
}

// ------------------------------------------------------------------
// k_main R14 = R12 structure, DUAL-CHAIN: one block = two adjacent n
// (grid 2048 x 256thr, 4 waves). Chains are independent dataflows in
// the same instruction stream -> in-wave ILP hides LDS/MFMA latency
// (counted lgkmcnt lets chain1's reads overlap chain0's MFMAs).
// Shared between chains: A-frags/biases (loaded once), P rows (L2),
// barriers. Softmax: wave0=chain0, wave1=chain1 in parallel.
// Final store: float2 (n, n+1 adjacent) -> halved write amplification.
// LDS 70.7KB -> 2 blocks/CU, __launch_bounds__(256,2) (256-reg class).
// ------------------------------------------------------------------
__global__ __launch_bounds__(256, 2) void k_main(float* __restrict__ out)
{
  __shared__ alignas(16) u16 buf[32768];   // chain c: H0@c*16384, H1@c*16384+8192; H2 overlays
  __shared__ float parts[2][4][128];
  __shared__ float attws[2][128];

  const int blk = blockIdx.x, b = blk >> 6, npair = (blk & 63) << 1, t = threadIdx.x;
  const char* ws = g_ws;
  const float* Pb  = (const float*)(ws + P_OFF);
  const float* Qb  = (const float*)(ws + Q_OFF);
  const float* SCb = (const float*)(ws + SC_OFF);
  const u16*   W1f = (const u16*)(ws + W1F_OFF);
  const float* b1f = (const float*)(ws + B1F_OFF);
  const u16*   W2f = (const u16*)(ws + W2F_OFF);
  const float* b2f = (const float*)(ws + B2F_OFF);
  const u16*   Wa0f= (const u16*)(ws + WA0F_OFF);
  const float* baf = (const float*)(ws + BAF_OFF);
  const float* wa1f= (const float*)(ws + WA1F_OFF);
  const float  ba1v= *(const float*)(ws + BA1F_OFF);

  const int lane = t & 63, wid = t >> 6, quad = lane >> 4, l16 = lane & 15;
  const int koff = quad * 8;

  u16* H0c[2] = { buf,        buf + 16384 };
  u16* H1c[2] = { buf + 8192, buf + 24576 };
  // H2 overlays H0c (rows 0..63) / full 32KB region per chain

  // hoisted A-fragments (global, L1-hot; shared by both chains)
  const short8 a1w0 = *(const short8*)(W1f + (wid * 16 + l16) * 64 + koff);
  const short8 a1w1 = *(const short8*)(W1f + (wid * 16 + l16) * 64 + 32 + koff);
  const short8 a2w00 = *(const short8*)(W2f + (wid * 32 + l16) * 64 + koff);
  const short8 a2w01 = *(const short8*)(W2f + (wid * 32 + l16) * 64 + 32 + koff);
  const short8 a2w10 = *(const short8*)(W2f + (wid * 32 + 16 + l16) * 64 + koff);
  const short8 a2w11 = *(const short8*)(W2f + (wid * 32 + 16 + l16) * 64 + 32 + koff);

  // ---- L0 x2: H0_c[edge][ch] = relu(Q[b,n_c] + P[b,j_c]) ----
  {
    const int k = t >> 1, half = t & 1;
    #pragma unroll
    for (int c = 0; c < 2; c++) {
      const int nc = npair + c;
      const int j = (k < 127) ? ((k < nc) ? k : (k + 1)) : nc;
      const float4* pr = (const float4*)(Pb + ((b << 7) + j) * 64 + half * 32);
      const float4* qr = (const float4*)(Qb + ((b << 7) + nc) * 64 + half * 32);
      #pragma unroll
      for (int ii = 0; ii < 4; ii++) {
        float4 p0 = pr[2 * ii],     q0 = qr[2 * ii];
        float4 p1 = pr[2 * ii + 1], q1 = qr[2 * ii + 1];
        uint4 sv;
        sv.x = pack2relu(q0.x + p0.x, q0.y + p0.y);
        sv.y = pack2relu(q0.z + p0.z, q0.w + p0.w);
        sv.z = pack2relu(q1.x + p1.x, q1.y + p1.y);
        sv.w = pack2relu(q1.z + p1.z, q1.w + p1.w);
        *(uint4*)(H0c[c] + sw64(k, half * 32 + ii * 8)) = sv;
      }
    }
  }
  __syncthreads();                                           // (1)

  // ---- GEMM1 x2: wave owns out-ch wid*16..+15; chains interleaved ----
  {
    const int rr = wid * 16 + quad * 4;
    const float4 bb = *(const float4*)(b1f + rr);
    floatx4 binit; binit[0] = bb.x; binit[1] = bb.y; binit[2] = bb.z; binit[3] = bb.w;
    floatx4 acc[2][8];
    #pragma unroll
    for (int c = 0; c < 2; c++)
      #pragma unroll
      for (int et = 0; et < 8; et++) acc[c][et] = binit;
    #pragma unroll
    for (int et = 0; et < 8; et++) {
      const int row = et * 16 + l16;
      short8 b00 = *(const short8*)(H0c[0] + sw64(row, koff));
      short8 b01 = *(const short8*)(H0c[0] + sw64(row, koff + 32));
      short8 b10 = *(const short8*)(H0c[1] + sw64(row, koff));
      short8 b11 = *(const short8*)(H0c[1] + sw64(row, koff + 32));
      acc[0][et] = MFMA16(a1w0, b00, acc[0][et]);
      acc[0][et] = MFMA16(a1w1, b01, acc[0][et]);
      acc[1][et] = MFMA16(a1w0, b10, acc[1][et]);
      acc[1][et] = MFMA16(a1w1, b11, acc[1][et]);
    }
    #pragma unroll
    for (int c = 0; c < 2; c++)
      #pragma unroll
      for (int et = 0; et < 8; et++) {
        uint2 sv;
        sv.x = pack2relu(acc[c][et][0], acc[c][et][1]);
        sv.y = pack2relu(acc[c][et][2], acc[c][et][3]);
        *(uint2*)(H1c[c] + sw64(et * 16 + l16, rr)) = sv;
      }
  }
  __syncthreads();                                           // (2)

  // ---- GEMM2 x2: wave owns out-ch wid*32..+31; register-staged ----
  {
    const int r2 = wid * 32 + quad * 4;
    const float4 bba = *(const float4*)(b2f + r2);
    const float4 bbb = *(const float4*)(b2f + r2 + 16);
    floatx4 ia; ia[0] = bba.x; ia[1] = bba.y; ia[2] = bba.z; ia[3] = bba.w;
    floatx4 ib; ib[0] = bbb.x; ib[1] = bbb.y; ib[2] = bbb.z; ib[3] = bbb.w;
    floatx4 acc[2][2][8];
    #pragma unroll
    for (int c = 0; c < 2; c++)
      #pragma unroll
      for (int et = 0; et < 8; et++) { acc[c][0][et] = ia; acc[c][1][et] = ib; }
    #pragma unroll
    for (int et = 0; et < 8; et++) {
      const int row = et * 16 + l16;
      short8 b00 = *(const short8*)(H1c[0] + sw64(row, koff));
      short8 b01 = *(const short8*)(H1c[0] + sw64(row, koff + 32));
      short8 b10 = *(const short8*)(H1c[1] + sw64(row, koff));
      short8 b11 = *(const short8*)(H1c[1] + sw64(row, koff + 32));
      acc[0][0][et] = MFMA16(a2w00, b00, acc[0][0][et]);
      acc[0][0][et] = MFMA16(a2w01, b01, acc[0][0][et]);
      acc[0][1][et] = MFMA16(a2w10, b00, acc[0][1][et]);
      acc[0][1][et] = MFMA16(a2w11, b01, acc[0][1][et]);
      acc[1][0][et] = MFMA16(a2w00, b10, acc[1][0][et]);
      acc[1][0][et] = MFMA16(a2w01, b11, acc[1][0][et]);
      acc[1][1][et] = MFMA16(a2w10, b10, acc[1][1][et]);
      acc[1][1][et] = MFMA16(a2w11, b11, acc[1][1][et]);
    }
    // pack before the barrier: 128 acc VGPRs -> 64 packed
    uint2 sv[2][2][8];
    #pragma unroll
    for (int c = 0; c < 2; c++)
      #pragma unroll
      for (int m = 0; m < 2; m++)
        #pragma unroll
        for (int et = 0; et < 8; et++) {
          sv[c][m][et].x = pack2relu(acc[c][m][et][0], acc[c][m][et][1]);
          sv[c][m][et].y = pack2relu(acc[c][m][et][2], acc[c][m][et][3]);
        }
    __syncthreads();                                         // (3) H1 reads done
    #pragma unroll
    for (int c = 0; c < 2; c++)
      #pragma unroll
      for (int m = 0; m < 2; m++) {
        const int cc = r2 + m * 16;
        #pragma unroll
        for (int et = 0; et < 8; et++)
          *(uint2*)(H0c[c] + sw128(et * 16 + l16, cc)) = sv[c][m][et];  // H2_c = region base
      }
  }

  // hoisted G3 A-frags (global, L1-hot; shared by both chains)
  short8 a3[4];
  #pragma unroll
  for (int ks = 0; ks < 4; ks++)
    a3[ks] = *(const short8*)(Wa0f + (wid * 16 + l16) * 128 + ks * 32 + koff);

  __syncthreads();                                           // (4)

  // hoisted epilogue loads
  float scv0 = 0.f, scv1 = 0.f;
  if (t < 128) {
    scv0 = SCb[((b << 7) + npair) * 128 + t];
    scv1 = SCb[((b << 7) + npair + 1) * 128 + t];
  }

  // ---- GEMM3 + logits x2: wave owns att-ch wid*16..+15 ----
  {
    const int rr = wid * 16 + quad * 4;
    const float4 bb = *(const float4*)(baf + rr);
    const float4 wv = *(const float4*)(wa1f + rr);
    floatx4 binit; binit[0] = bb.x; binit[1] = bb.y; binit[2] = bb.z; binit[3] = bb.w;
    floatx4 acc[2][8];
    #pragma unroll
    for (int c = 0; c < 2; c++)
      #pragma unroll
      for (int et = 0; et < 8; et++) acc[c][et] = binit;
    #pragma unroll
    for (int et = 0; et < 8; et++) {
      const int row = et * 16 + l16;
      #pragma unroll
      for (int ks = 0; ks < 4; ks++) {
        short8 bf0 = *(const short8*)(H0c[0] + sw128(row, koff + ks * 32));
        short8 bf1 = *(const short8*)(H0c[1] + sw128(row, koff + ks * 32));
        acc[0][et] = MFMA16(a3[ks], bf0, acc[0][et]);
        acc[1][et] = MFMA16(a3[ks], bf1, acc[1][et]);
      }
    }
    #pragma unroll
    for (int c = 0; c < 2; c++)
      #pragma unroll
      for (int et = 0; et < 8; et++) {
        float p = wv.x * fmaxf(acc[c][et][0], 0.f) + wv.y * fmaxf(acc[c][et][1], 0.f)
                + wv.z * fmaxf(acc[c][et][2], 0.f) + wv.w * fmaxf(acc[c][et][3], 0.f);
        p += __shfl_xor(p, 16); p += __shfl_xor(p, 32);
        if (quad == 0) parts[c][wid][et * 16 + l16] = p;
      }
  }

  // ---- fts prefetch x2: H2 final since barrier (4) ----
  const int chg = t & 15, eg = t >> 4;   // 8 ch x 8 edges per thread
  uint4 hv[2][8];
  #pragma unroll
  for (int c = 0; c < 2; c++)
    #pragma unroll
    for (int i = 0; i < 8; i++)
      hv[c][i] = *(const uint4*)(H0c[c] + sw128(eg * 8 + i, chg * 8));

  __syncthreads();                                           // (5)

  // ---- softmax over 127 edges: wave0 -> chain0, wave1 -> chain1 ----
  if (wid < 2) {
    const int c = wid;
    float a0 = parts[c][0][lane] + parts[c][1][lane] + parts[c][2][lane] + parts[c][3][lane] + ba1v;
    float a1 = (lane == 63) ? -1e30f
             : (parts[c][0][lane + 64] + parts[c][1][lane + 64] + parts[c][2][lane + 64] + parts[c][3][lane + 64] + ba1v);
    float mx = fmaxf(a0, a1);
    #pragma unroll
    for (int off = 32; off >= 1; off >>= 1) mx = fmaxf(mx, __shfl_xor(mx, off));
    float e0 = expf(a0 - mx), e1 = expf(a1 - mx);
    float sm = e0 + e1;
    #pragma unroll
    for (int off = 32; off >= 1; off >>= 1) sm += __shfl_xor(sm, off);
    float inv = 1.f / sm;
    attws[c][lane] = e0 * inv;
    attws[c][lane + 64] = e1 * inv;   // attw[127] = 0
  }
  __syncthreads();                                           // (6)

  // ---- fts x2 (H2 values already in hv) ----
  #pragma unroll
  for (int c = 0; c < 2; c++) {
    float fa[8];
    #pragma unroll
    for (int k = 0; k < 8; k++) fa[k] = 0.f;
    #pragma unroll
    for (int i = 0; i < 8; i++) {
      const float w = attws[c][eg * 8 + i];
      uint4 v = hv[c][i];
      unsigned u;
      u = v.x; fa[0] += w * bits2f(u << 16); fa[1] += w * bits2f(u & 0xffff0000u);
      u = v.y; fa[2] += w * bits2f(u << 16); fa[3] += w * bits2f(u & 0xffff0000u);
      u = v.z; fa[4] += w * bits2f(u << 16); fa[5] += w * bits2f(u & 0xffff0000u);
      u = v.w; fa[6] += w * bits2f(u << 16); fa[7] += w * bits2f(u & 0xffff0000u);
    }
    #pragma unroll
    for (int k = 0; k < 8; k++) { fa[k] += __shfl_xor(fa[k], 16); fa[k] += __shfl_xor(fa[k], 32); }
    if (lane < 16) {
      #pragma unroll
      for (int k = 0; k < 8; k++) parts[c][wid][chg * 8 + k] = fa[k];
    }
  }
  __syncthreads();                                           // (7)

  if (t < 128) {
    float f0 = parts[0][0][t] + parts[0][1][t] + parts[0][2][t] + parts[0][3][t];
    float f1 = parts[1][0][t] + parts[1][1][t] + parts[1][2][t] + parts[1][3][t];
    float2 o;
    o.x = fmaxf(scv0 + f0, 0.f);
    o.y = fmaxf(scv1 + f1, 0.f);
    *(float2*)(out + (((b << 7) + t) << 7) + npair) = o;
  }
}

// ------------------------------------------------------------------
extern "C" void kernel_launch(void* const* d_in, const int* in_sizes, int n_in,
                              void* d_out, int out_size, void* d_ws, size_t ws_size,
                              hipStream_t stream)
{
  (void)d_ws; (void)ws_size; (void)in_sizes; (void)n_in; (void)out_size;
  const float* feat = (const float*)d_in[0];
  const float *w0 = (const float*)d_in[1],  *g0 = (const float*)d_in[2],  *b0 = (const float*)d_in[3],  *m0 = (const float*)d_in[4],  *v0 = (const float*)d_in[5];
  const float *w1 = (const float*)d_in[6],  *g1 = (const float*)d_in[7],  *b1 = (const float*)d_in[8],  *m1 = (const float*)d_in[9],  *v1 = (const float*)d_in[10];
  const float *w2 = (const float*)d_in[11], *g2 = (const float*)d_in[12], *b2 = (const float*)d_in[13], *m2 = (const float*)d_in[14], *v2 = (const float*)d_in[15];
  const float *wa0= (const float*)d_in[16], *ga = (const float*)d_in[17], *ba = (const float*)d_in[18], *ma = (const float*)d_in[19], *va = (const float*)d_in[20];
  const float *wa1= (const float*)d_in[21], *ba1= (const float*)d_in[22];
  const float *wsc= (const float*)d_in[23], *gsc= (const float*)d_in[24], *bsc= (const float*)d_in[25], *msc= (const float*)d_in[26], *vsc= (const float*)d_in[27];

  k_pre<<<dim3(513), dim3(256), 0, stream>>>(
      feat, w0, g0, b0, m0, v0, w1, g1, b1, m1, v1, w2, g2, b2, m2, v2,
      wa0, ga, ba, ma, va, wa1, ba1, wsc, gsc, bsc, msc, vsc);
  k_main<<<dim3(2048), dim3(256), 0, stream>>>((float*)d_out);
}